// Round 4
// baseline (210.813 us; speedup 1.0000x reference)
//
#include <hip/hip_runtime.h>
#include <hip/hip_bf16.h>
#include <cstdint>
#include <cstddef>

#define B_N   32
#define CIN_  128
#define COUT_ 128
#define KW_   7
#define L_    4096
#define PAD_  3
#define NW_   128      // w-positions per block tile
#define BC_   32       // channels per K-chunk
#define NPOS_ 136      // staged sX rows (134 used, padded)
#define RPB   4104     // exT rows per batch: r = l + 3, guards r<3 and r>4098
#define NWELEM (KW_ * COUT_ * CIN_)   // 114688
#define NGUARD (B_N * 8 * CIN_)       // 32768 guard elements

typedef __attribute__((ext_vector_type(8))) short  bf16x8;
typedef __attribute__((ext_vector_type(4))) float  f32x4;

__device__ __forceinline__ void gl2lds16(const void* g, void* l) {
    __builtin_amdgcn_global_load_lds(
        (const __attribute__((address_space(1))) unsigned int*)g,
        (__attribute__((address_space(3))) unsigned int*)l, 16, 0, 0);
}

// ewb[k][o][c] = bf16(exp(W[o][c][k]))  +  zero exT guard rows (l-padding).
__global__ void prep_wg_kernel(const float* __restrict__ w,
                               __hip_bfloat16* __restrict__ ewb,
                               __hip_bfloat16* __restrict__ exT) {
    int idx = blockIdx.x * 256 + threadIdx.x;
    if (idx < NWELEM) {
        int c = idx & 127, rest = idx >> 7;
        int o = rest & 127, k = rest >> 7;
        ewb[idx] = __float2bfloat16(__expf(w[(o * CIN_ + c) * KW_ + k]));
    } else if (idx < NWELEM + NGUARD) {
        int j  = idx - NWELEM;
        int b  = j >> 10, rr = (j >> 7) & 7, c = j & 127;
        int r  = (rr < 3) ? rr : (4096 + rr);     // rows 0,1,2 and 4099..4103
        exT[((size_t)b * RPB + r) * CIN_ + c] = __float2bfloat16(0.0f);
    }
}

// exT[b][l+3][c] = bf16(exp(x[b][c][l])) -- exp + transpose via LDS tile.
// tileT row l (pitch 136 elems = 272 B); channel 8-blocks XOR-swizzled by
// (l>>2)&15 so scalar b16 writes spread banks; b128 reads stay aligned.
__global__ __launch_bounds__(256) void exp_x_kernel(
        const float* __restrict__ x, __hip_bfloat16* __restrict__ exT) {
    __shared__ __align__(16) __hip_bfloat16 tileT[64 * 136];   // 17408 B
    const int b  = blockIdx.y;
    const int l0 = blockIdx.x * 64;
    const int tid = threadIdx.x;
    const float* xb = x + (size_t)b * CIN_ * L_ + l0;

    #pragma unroll
    for (int i = 0; i < 8; ++i) {
        int idx = tid + 256 * i;
        int c   = idx >> 4;               // 0..127
        int lv4 = (idx & 15) * 4;         // l offset 0..60
        f32x4 v = *(const f32x4*)(xb + (size_t)c * L_ + lv4);
        #pragma unroll
        for (int k2 = 0; k2 < 4; ++k2) {
            int l  = lv4 + k2;
            int sw = (l >> 2) & 15;
            tileT[l * 136 + (c ^ (sw << 3))] = __float2bfloat16(__expf(v[k2]));
        }
    }
    __syncthreads();

    __hip_bfloat16* dst = exT + ((size_t)b * RPB + l0 + PAD_) * CIN_;
    #pragma unroll
    for (int i = 0; i < 4; ++i) {
        int idx = tid + 256 * i;
        int l  = idx >> 4;                // 16 lanes per row -> 256 B coalesced
        int gc = idx & 15;                // channel granule (8 ch)
        int sw = (l >> 2) & 15;
        bf16x8 vv = *(const bf16x8*)&tileT[l * 136 + ((gc ^ sw) << 3)];
        *(bf16x8*)(dst + (size_t)l * CIN_ + gc * 8) = vv;
    }
}

// Pure MFMA conv: sX staged via global_load_lds (double-buffered, one barrier
// per 32-channel chunk = 112 MFMAs/barrier); weights direct from L2-resident ewb.
__global__ __launch_bounds__(256, 3) void tropconv_kernel(
        const __hip_bfloat16* __restrict__ exT,
        const __hip_bfloat16* __restrict__ ewb,
        const float* __restrict__ bias,
        float* __restrict__ out) {
    __shared__ __align__(16) __hip_bfloat16 sX[2][NPOS_ * BC_];   // 2 x 8704 B

    const int tid  = threadIdx.x;
    const int lane = tid & 63;
    const int wave = tid >> 6;
    const int wm   = wave >> 1;
    const int wn   = wave & 1;
    const int l15  = lane & 15;
    const int q    = lane >> 4;

    const int b  = blockIdx.y;
    const int w0 = blockIdx.x * NW_;
    const __hip_bfloat16* exb = exT + ((size_t)b * RPB + w0) * CIN_;  // row p

    f32x4 acc[4][4];
    #pragma unroll
    for (int i = 0; i < 4; ++i)
        #pragma unroll
        for (int j = 0; j < 4; ++j)
            acc[i][j] = (f32x4){0.f, 0.f, 0.f, 0.f};

    // stage chunk (c0) into buffer bufi: 544 16B granules, lane-consecutive LDS
    #define STAGE(c0, bufi) do {                                              \
        _Pragma("unroll")                                                     \
        for (int s = 0; s < 2; ++s) {                                         \
            int g = tid + 256 * s;                                            \
            int p = g >> 2, j = g & 3;                                        \
            gl2lds16(exb + (size_t)p * CIN_ + (c0) + j * 8,                   \
                     (void*)&sX[bufi][g * 8]);                                \
        }                                                                     \
        if (tid < 32) {                                                       \
            int g = tid + 512;                                                \
            int p = g >> 2, j = g & 3;                                        \
            gl2lds16(exb + (size_t)p * CIN_ + (c0) + j * 8,                   \
                     (void*)&sX[bufi][g * 8]);                                \
        }                                                                     \
    } while (0)

    STAGE(0, 0);
    __syncthreads();   // vmcnt(0) drain: chunk 0 resident

    for (int c = 0; c < 4; ++c) {
        const int c0 = c * BC_;
        if (c < 3) STAGE(c0 + BC_, (c + 1) & 1);   // prefetch next chunk

        const __hip_bfloat16* buf = sX[c & 1];
        #pragma unroll
        for (int t = 0; t < KW_; ++t) {
            bf16x8 af[4], bx[4];
            #pragma unroll
            for (int mi = 0; mi < 4; ++mi) {
                int o = wm * 64 + mi * 16 + l15;       // A: m = lane&15
                af[mi] = *(const bf16x8*)(ewb + ((size_t)t * COUT_ + o) * CIN_
                                          + c0 + q * 8);
            }
            #pragma unroll
            for (int ni = 0; ni < 4; ++ni) {
                int p = wn * 64 + ni * 16 + l15 + t;   // input pos = out w + tap
                bx[ni] = *(const bf16x8*)&buf[(p * 4 + q) * 8];
            }
            #pragma unroll
            for (int mi = 0; mi < 4; ++mi)
                #pragma unroll
                for (int ni = 0; ni < 4; ++ni)
                    acc[mi][ni] = __builtin_amdgcn_mfma_f32_16x16x32_bf16(
                        af[mi], bx[ni], acc[mi][ni], 0, 0, 0);
        }
        __syncthreads();   // readers done with buf[c&1]; prefetch drained
    }

    // epilogue: y = log(s) + bias[o]; C/D: col=lane&15 (w), row=q*4+reg (cout)
    float* outb = out + (size_t)b * COUT_ * L_;
    #pragma unroll
    for (int mi = 0; mi < 4; ++mi) {
        #pragma unroll
        for (int r = 0; r < 4; ++r) {
            int o = wm * 64 + mi * 16 + q * 4 + r;
            float bv = bias[o];
            #pragma unroll
            for (int ni = 0; ni < 4; ++ni) {
                int w = w0 + wn * 64 + ni * 16 + l15;
                outb[(size_t)o * L_ + w] = __logf(acc[mi][ni][r]) + bv;
            }
        }
    }
    #undef STAGE
}

extern "C" void kernel_launch(void* const* d_in, const int* in_sizes, int n_in,
                              void* d_out, int out_size, void* d_ws, size_t ws_size,
                              hipStream_t stream) {
    const float* x    = (const float*)d_in[0];   // (32,128,4096) f32
    const float* wgt  = (const float*)d_in[1];   // (128,128,7)   f32
    const float* bias = (const float*)d_in[2];   // (128,)        f32
    float* out = (float*)d_out;                  // (32,128,4096) f32

    // workspace layout: exT (32 x 4104 x 128 bf16 = 33,619,968 B), then ewb
    __hip_bfloat16* exT = (__hip_bfloat16*)d_ws;
    __hip_bfloat16* ewb = (__hip_bfloat16*)((char*)d_ws + (size_t)B_N * RPB * CIN_ * 2);

    prep_wg_kernel<<<(NWELEM + NGUARD + 255) / 256, 256, 0, stream>>>(wgt, ewb, exT);
    exp_x_kernel<<<dim3(L_ / 64, B_N), 256, 0, stream>>>(x, exT);
    tropconv_kernel<<<dim3(L_ / NW_, B_N), 256, 0, stream>>>(exT, ewb, bias, out);
}

// Round 5
// 147.459 us; speedup vs baseline: 1.4296x; 1.4296x over previous
//
#include <hip/hip_runtime.h>
#include <hip/hip_bf16.h>
#include <cstdint>
#include <cstddef>

#define B_N   32
#define CIN_  128
#define COUT_ 128
#define KW_   7
#define L_    4096
#define PAD_  3
#define NW_   128      // w-positions per block tile
#define BC_   32       // channels per K-chunk
#define RPB   4104     // exT rows per batch: r = l + 3, guards r<3 and r>4098
#define NWELEM (KW_ * COUT_ * CIN_)   // 114688
#define NGUARD (B_N * 8 * CIN_)       // 32768

#define SW_ELEMS (KW_ * COUT_ * BC_)  // 28672 bf16 = 57344 B
#define SX_ROWS  192                  // staged rows (134 used; padded so total granules % 256 == 0)
#define SX_ELEMS (SX_ROWS * BC_)      // 6144 bf16 = 12288 B
#define NGRAN_W  (SW_ELEMS / 8)       // 3584 16B-granules
#define NGRAN_T  ((SW_ELEMS + SX_ELEMS) / 8)  // 4352 = 17 * 256

typedef __attribute__((ext_vector_type(8))) short  bf16x8;
typedef __attribute__((ext_vector_type(4))) float  f32x4;

__device__ __forceinline__ void gl2lds16(const void* g, void* l) {
    __builtin_amdgcn_global_load_lds(
        (const __attribute__((address_space(1))) unsigned int*)g,
        (__attribute__((address_space(3))) unsigned int*)l, 16, 0, 0);
}

// ewb[k][o][c] = bf16(exp(W[o][c][k]))  +  zero exT guard rows (l-padding).
__global__ void prep_wg_kernel(const float* __restrict__ w,
                               __hip_bfloat16* __restrict__ ewb,
                               __hip_bfloat16* __restrict__ exT) {
    int idx = blockIdx.x * 256 + threadIdx.x;
    if (idx < NWELEM) {
        int c = idx & 127, rest = idx >> 7;
        int o = rest & 127, k = rest >> 7;
        ewb[idx] = __float2bfloat16(__expf(w[(o * CIN_ + c) * KW_ + k]));
    } else if (idx < NWELEM + NGUARD) {
        int j  = idx - NWELEM;
        int b  = j >> 10, rr = (j >> 7) & 7, c = j & 127;
        int r  = (rr < 3) ? rr : (4096 + rr);     // rows 0,1,2 and 4099..4103
        exT[((size_t)b * RPB + r) * CIN_ + c] = __float2bfloat16(0.0f);
    }
}

// exT[b][l+3][c] = bf16(exp(x[b][c][l])) -- exp + transpose via LDS tile.
__global__ __launch_bounds__(256) void exp_x_kernel(
        const float* __restrict__ x, __hip_bfloat16* __restrict__ exT) {
    __shared__ __align__(16) __hip_bfloat16 tileT[64 * 136];   // 17408 B
    const int b  = blockIdx.y;
    const int l0 = blockIdx.x * 64;
    const int tid = threadIdx.x;
    const float* xb = x + (size_t)b * CIN_ * L_ + l0;

    #pragma unroll
    for (int i = 0; i < 8; ++i) {
        int idx = tid + 256 * i;
        int c   = idx >> 4;               // 0..127
        int lv4 = (idx & 15) * 4;         // l offset 0..60
        f32x4 v = *(const f32x4*)(xb + (size_t)c * L_ + lv4);
        #pragma unroll
        for (int k2 = 0; k2 < 4; ++k2) {
            int l  = lv4 + k2;
            int sw = (l >> 2) & 15;
            tileT[l * 136 + (c ^ (sw << 3))] = __float2bfloat16(__expf(v[k2]));
        }
    }
    __syncthreads();

    __hip_bfloat16* dst = exT + ((size_t)b * RPB + l0 + PAD_) * CIN_;
    #pragma unroll
    for (int i = 0; i < 4; ++i) {
        int idx = tid + 256 * i;
        int l  = idx >> 4;                // 16 lanes per row -> 256 B coalesced
        int gc = idx & 15;                // channel granule (8 ch)
        int sw = (l >> 2) & 15;
        bf16x8 vv = *(const bf16x8*)&tileT[l * 136 + ((gc ^ sw) << 3)];
        *(bf16x8*)(dst + (size_t)l * CIN_ + gc * 8) = vv;
    }
}

// Conv GEMM: per 32-ch chunk stage sW(56KB)+sX(12KB) via global_load_lds,
// one barrier, pure LDS+MFMA phase (112 MFMAs/wave), barrier. No global
// loads inside compute -> no vmcnt serialization. 66KB LDS -> 2 blocks/CU.
__global__ __launch_bounds__(256, 2) void tropconv_kernel(
        const __hip_bfloat16* __restrict__ exT,
        const __hip_bfloat16* __restrict__ ewb,
        const float* __restrict__ bias,
        float* __restrict__ out) {
    __shared__ __align__(16) __hip_bfloat16 smem[SW_ELEMS + SX_ELEMS]; // 69632 B
    __hip_bfloat16* sW = smem;             // [t*128+o][32ch], 64 B rows
    __hip_bfloat16* sX = smem + SW_ELEMS;  // [p][32ch], 64 B rows

    const int tid  = threadIdx.x;
    const int lane = tid & 63;
    const int wave = tid >> 6;
    const int wm   = wave >> 1;
    const int wn   = wave & 1;
    const int l15  = lane & 15;
    const int q    = lane >> 4;

    const int b  = blockIdx.y;
    const int w0 = blockIdx.x * NW_;
    const __hip_bfloat16* exb = exT + ((size_t)b * RPB + w0) * CIN_;

    f32x4 acc[4][4];
    #pragma unroll
    for (int i = 0; i < 4; ++i)
        #pragma unroll
        for (int j = 0; j < 4; ++j)
            acc[i][j] = (f32x4){0.f, 0.f, 0.f, 0.f};

    for (int c = 0; c < 4; ++c) {
        const int c0 = c * BC_;

        // ---- stage: 4352 granules, 17 uniform rounds, lane-consecutive LDS.
        // sW granule g: row=g>>2 (=t*128+o), j=g&3 -> ewb[row*128 + c0 + j*8]
        // sX granule gx: p=gx>>2, j=gx&3 -> exb[p*128 + c0 + j*8]
        // (rows >=134 stage garbage from within d_ws; never read by MFMAs)
        #pragma unroll
        for (int s = 0; s < 17; ++s) {
            int g = tid + 256 * s;
            if (g < NGRAN_W) {
                int row = g >> 2, j = g & 3;
                gl2lds16(ewb + ((size_t)row << 7) + c0 + j * 8, &sW[g * 8]);
            } else {
                int gx = g - NGRAN_W;
                int p = gx >> 2, j = gx & 3;
                gl2lds16(exb + ((size_t)p << 7) + c0 + j * 8, &sX[gx * 8]);
            }
        }
        __syncthreads();   // drain global_load_lds; chunk resident

        #pragma unroll
        for (int t = 0; t < KW_; ++t) {
            bf16x8 af[4], bx[4];
            #pragma unroll
            for (int mi = 0; mi < 4; ++mi) {
                int o = wm * 64 + mi * 16 + l15;       // A: m = lane&15
                af[mi] = *(const bf16x8*)&sW[(t * COUT_ + o) * BC_ + q * 8];
            }
            #pragma unroll
            for (int ni = 0; ni < 4; ++ni) {
                int p = wn * 64 + ni * 16 + l15 + t;   // input pos = out w + tap
                bx[ni] = *(const bf16x8*)&sX[p * BC_ + q * 8];
            }
            #pragma unroll
            for (int mi = 0; mi < 4; ++mi)
                #pragma unroll
                for (int ni = 0; ni < 4; ++ni)
                    acc[mi][ni] = __builtin_amdgcn_mfma_f32_16x16x32_bf16(
                        af[mi], bx[ni], acc[mi][ni], 0, 0, 0);
        }
        __syncthreads();   // all readers done before restage
    }

    // epilogue: y = log(s) + bias[o]; C/D: col=lane&15 (w), row=q*4+reg (cout)
    float* outb = out + (size_t)b * COUT_ * L_;
    #pragma unroll
    for (int mi = 0; mi < 4; ++mi) {
        #pragma unroll
        for (int r = 0; r < 4; ++r) {
            int o = wm * 64 + mi * 16 + q * 4 + r;
            float bv = bias[o];
            #pragma unroll
            for (int ni = 0; ni < 4; ++ni) {
                int w = w0 + wn * 64 + ni * 16 + l15;
                outb[(size_t)o * L_ + w] = __logf(acc[mi][ni][r]) + bv;
            }
        }
    }
}

extern "C" void kernel_launch(void* const* d_in, const int* in_sizes, int n_in,
                              void* d_out, int out_size, void* d_ws, size_t ws_size,
                              hipStream_t stream) {
    const float* x    = (const float*)d_in[0];   // (32,128,4096) f32
    const float* wgt  = (const float*)d_in[1];   // (128,128,7)   f32
    const float* bias = (const float*)d_in[2];   // (128,)        f32
    float* out = (float*)d_out;                  // (32,128,4096) f32

    // workspace: exT (32 x 4104 x 128 bf16 = 33,619,968 B), then ewb (229 KB)
    __hip_bfloat16* exT = (__hip_bfloat16*)d_ws;
    __hip_bfloat16* ewb = (__hip_bfloat16*)((char*)d_ws + (size_t)B_N * RPB * CIN_ * 2);

    prep_wg_kernel<<<(NWELEM + NGUARD + 255) / 256, 256, 0, stream>>>(wgt, ewb, exT);
    exp_x_kernel<<<dim3(L_ / 64, B_N), 256, 0, stream>>>(x, exT);
    tropconv_kernel<<<dim3(L_ / NW_, B_N), 256, 0, stream>>>(exT, ewb, bias, out);
}